// Round 20
// baseline (77.552 us; speedup 1.0000x reference)
//
#include <hip/hip_runtime.h>

#define BB   8
#define NBL  2000
#define RR   10000
#define XDIM 2000

// ---------------- kernel A (split-K×4, R8 geometry; guard-diet only):
// mem2[q][b][nb] = x·W_fc[nb*5+q] + biases. 2000 blocks × 256 thr, 4 waves = quarters.
// Waves 0-2: cols < 1536 always valid -> guard-free loads (~104 cndmask/wave saved).
// Wave 3 keeps the tail guard. Reduce = proven 6-level shfl_xor (DPP attempt was
// a prefix-sum bug — reverted).
__global__ __launch_bounds__(256, 4) void kA_gemm(
    const float* __restrict__ in1, const float* __restrict__ in2,
    const float* __restrict__ in3, const float* __restrict__ in4,
    const float* __restrict__ in5,
    const float* __restrict__ Wfc, const float* __restrict__ bfc,
    const float* __restrict__ bfv, float* __restrict__ mem2,
    unsigned* __restrict__ counter)
{
    // re-arm the kernel-B barrier every call (stream order publishes it before kB)
    if (blockIdx.x == 0 && threadIdx.x == 0) *counter = 0u;

    const int tid  = threadIdx.x;
    const int wave = tid >> 6, lane = tid & 63;     // wave = column quarter 0..3
    const int nb    = blockIdx.x;                   // 0..1999
    const int rbase = nb * 5;

    float acc[5][BB];
    #pragma unroll
    for (int q = 0; q < 5; ++q)
        #pragma unroll
        for (int b = 0; b < BB; ++b) acc[q][b] = 0.f;

    if (wave < 3) {
        // ---- guard-free path: cols 0..1532 (+lane*4), always < XDIM
        #pragma unroll
        for (int i = 0; i < 2; ++i) {
            const int col = wave * 512 + i * 256 + (lane << 2);
            const int wh  = col / 400;
            const int off = col - wh * 400;
            const float* xp = in1;
            xp = (wh == 1) ? in2 : xp;
            xp = (wh == 2) ? in3 : xp;
            xp = (wh == 3) ? in4 : xp;

            float4 w[5];
            #pragma unroll
            for (int q = 0; q < 5; ++q)
                w[q] = *(const float4*)(Wfc + (size_t)(rbase + q) * XDIM + col);

            #pragma unroll
            for (int b = 0; b < BB; ++b) {
                const float4 xv = *(const float4*)(xp + b * 400 + off);
                #pragma unroll
                for (int q = 0; q < 5; ++q)
                    acc[q][b] += w[q].x * xv.x + w[q].y * xv.y
                               + w[q].z * xv.z + w[q].w * xv.w;
            }
        }
    } else {
        // ---- tail path (wave 3): cols 1536..2044, guard col < 2000
        #pragma unroll
        for (int i = 0; i < 2; ++i) {
            const int col = 1536 + i * 256 + (lane << 2);
            const bool valid = col < XDIM;
            const int wh  = col / 400;              // 3,4 (5 only when invalid)
            const int off = col - wh * 400;
            const float* xp = (wh == 4) ? in5 : in4;

            float4 w[5];
            #pragma unroll
            for (int q = 0; q < 5; ++q)
                w[q] = valid ? *(const float4*)(Wfc + (size_t)(rbase + q) * XDIM + col)
                             : make_float4(0.f, 0.f, 0.f, 0.f);

            #pragma unroll
            for (int b = 0; b < BB; ++b) {
                const float4 xv = valid ? *(const float4*)(xp + b * 400 + off)
                                        : make_float4(0.f, 0.f, 0.f, 0.f);
                #pragma unroll
                for (int q = 0; q < 5; ++q)
                    acc[q][b] += w[q].x * xv.x + w[q].y * xv.y
                               + w[q].z * xv.z + w[q].w * xv.w;
            }
        }
    }

    // intra-wave reduce (proven 6-level shfl_xor) -> LDS partials -> wave 0 finalizes
    __shared__ float part[4][5][BB];                // [wave][q][b], 640 B
    #pragma unroll
    for (int q = 0; q < 5; ++q) {
        #pragma unroll
        for (int b = 0; b < BB; ++b) {
            float v = acc[q][b];
            #pragma unroll
            for (int o = 32; o >= 1; o >>= 1) v += __shfl_xor(v, o, 64);
            if (lane == 0) part[wave][q][b] = v;
        }
    }
    __syncthreads();

    if (wave == 0 && lane < 40) {                   // 40 outputs: q = lane>>3, b = lane&7
        const int q = lane >> 3, b = lane & 7;
        const int r = rbase + q;
        const float v = part[0][q][b] + part[1][q][b] + part[2][q][b] + part[3][q][b];
        mem2[(q * BB + b) * NBL + nb] = v + bfc[r] + bfv[r] + 0.05f;
    }
}

// ---------------- kernel B (R15 champion, byte-identical): select+spike -> barrier
// -> GEMV with W_mlp LDS-staged by non-select waves during the spin window.
__device__ __forceinline__ unsigned sortkey(float f) {
    unsigned u = __float_as_uint(f);
    return (u & 0x80000000u) ? ~u : (u | 0x80000000u);
}
__device__ __forceinline__ float unsortkey(unsigned u) {
    unsigned ub = (u & 0x80000000u) ? (u ^ 0x80000000u) : ~u;
    return __uint_as_float(ub);
}

__global__ __launch_bounds__(512) void kB_spike_out(
    const float* __restrict__ mem2, const float* __restrict__ Wmlp,
    const float* __restrict__ bmlp, float* __restrict__ spike_out,
    float* __restrict__ out, unsigned* __restrict__ counter)
{
    __shared__ float wlds[RR];                       // 40 KB: W_mlp row o
    const int tid = threadIdx.x;
    const int blk = blockIdx.x;                      // 100 blocks
    const bool is_sel = (blk < 40) && (tid < 64);    // select wave

    // ---- stage W_mlp[o] into LDS (all non-select threads; overlaps select below)
    if (!is_sel) {
        const int nstage = (blk < 40) ? 448 : 512;
        const int stid   = (blk < 40) ? (tid - 64) : tid;
        for (int j = stid; j < 2500; j += nstage) {
            const int col = j * 4;
            *(float4*)&wlds[col] = *(const float4*)(Wmlp + (size_t)blk * RR + col);
        }
    }

    // ---- phase A: blocks 0..39, wave 0 only — exact order stats + spike write
    if (is_sel) {
        const int b = blk / 5, k = blk - b * 5;
        const int lane = tid;
        const float* src = mem2 + (k * BB + b) * NBL;

        float    f[32];
        unsigned u[32];
        #pragma unroll
        for (int i = 0; i < 32; ++i) {
            int nb = i * 64 + lane;
            f[i] = (nb < NBL) ? src[nb] : 0.f;
            u[i] = (nb < NBL) ? sortkey(f[i]) : 0u;  // pad key = smallest
        }

        // rank-159 (160th largest): max X with count(u >= X) >= 160 (ballot+popc)
        unsigned X = 0;
        for (int bit = 31; bit >= 0; --bit) {
            unsigned cand = X | (1u << bit);
            int c = 0;
            #pragma unroll
            for (int i = 0; i < 32; ++i)
                c += (int)__popcll(__ballot(u[i] >= cand));
            if (c >= 160) X = cand;
        }
        const unsigned q2u = X;                      // mem_q2 (rank 159)

        int cge = 0;
        #pragma unroll
        for (int i = 0; i < 32; ++i)
            cge += (int)__popcll(__ballot(u[i] >= q2u));

        unsigned q1u;
        if (cge >= 161) {
            q1u = q2u;                               // ties reach rank 160
        } else {
            unsigned m = 0;
            #pragma unroll
            for (int i = 0; i < 32; ++i)
                if (u[i] < q2u && u[i] > m) m = u[i];
            #pragma unroll
            for (int o = 32; o >= 1; o >>= 1) {
                unsigned ot = __shfl_xor(m, o, 64);
                m = (ot > m) ? ot : m;
            }
            q1u = m;                                 // mem_q1 (rank 160)
        }

        const float q2 = unsortkey(q2u), q1 = unsortkey(q1u);
        const float nps = q1 + (q2 - q1) * 0.2f;

        #pragma unroll
        for (int i = 0; i < 32; ++i) {
            int nb = i * 64 + lane;
            if (nb < NBL)
                spike_out[b * RR + nb * 5 + k] = (f[i] - nps > 0.1f) ? 1.0f : 0.0f;
        }
        __threadfence();                             // release spike stores
        if (lane == 0) atomicAdd(counter, 1u);       // device-scope by default
    }

    // ---- barrier: all 100 blocks co-resident (<=256 CUs), spin on counter
    __syncthreads();                                 // also fences the LDS staging
    if (tid == 0) {
        while (__hip_atomic_load(counter, __ATOMIC_ACQUIRE, __HIP_MEMORY_SCOPE_AGENT) < 40u)
            __builtin_amdgcn_s_sleep(2);
        __threadfence();                             // belt-and-braces acquire
    }
    __syncthreads();

    // ---- phase B: block = output column o; out[b][o] = spike[b]·W_mlp[o] + b_mlp[o]
    const int o = blk;
    const int wave = tid >> 6, lane = tid & 63;

    float acc[BB];
    #pragma unroll
    for (int b = 0; b < BB; ++b) acc[b] = 0.f;

    #pragma unroll
    for (int i = 0; i < 5; ++i) {
        int col = i * 2048 + tid * 4;                // 512 thr × f4 = 2048 floats/iter
        if (col < RR) {                              // last valid f4 at 9996
            float4 w = *(const float4*)&wlds[col];
            #pragma unroll
            for (int b = 0; b < BB; ++b) {
                float4 s = *(const float4*)(spike_out + b * RR + col);
                acc[b] += w.x * s.x + w.y * s.y + w.z * s.z + w.w * s.w;
            }
        }
    }

    __shared__ float red[8][BB];
    #pragma unroll
    for (int b = 0; b < BB; ++b) {
        float v = acc[b];
        #pragma unroll
        for (int off = 32; off >= 1; off >>= 1) v += __shfl_xor(v, off, 64);
        if (lane == 0) red[wave][b] = v;
    }
    __syncthreads();
    if (tid < BB) {
        float v = 0.f;
        #pragma unroll
        for (int w = 0; w < 8; ++w) v += red[w][tid];
        out[tid * 100 + o] = v + bmlp[o];
    }
}

extern "C" void kernel_launch(void* const* d_in, const int* in_sizes, int n_in,
                              void* d_out, int out_size, void* d_ws, size_t ws_size,
                              hipStream_t stream) {
    const float* in1  = (const float*)d_in[0];
    const float* in2  = (const float*)d_in[1];
    const float* in3  = (const float*)d_in[2];
    const float* in4  = (const float*)d_in[3];
    const float* in5  = (const float*)d_in[4];
    const float* Wfc  = (const float*)d_in[5];
    const float* bfc  = (const float*)d_in[6];
    // d_in[7] = W_fv : multiplied by zero spikes — never read (saves 400 MB)
    const float* bfv  = (const float*)d_in[8];
    const float* Wmlp = (const float*)d_in[9];
    const float* bmlp = (const float*)d_in[10];

    float* out   = (float*)d_out;          // 8*100 = 800 floats
    float* spike = out + 800;              // 8*10000 floats (r_sumspike)

    float*    mem2    = (float*)d_ws;      // 80000 floats, layout [q][b][nb]
    unsigned* counter = (unsigned*)((char*)d_ws + 80000 * sizeof(float));

    kA_gemm<<<2000, 256, 0, stream>>>(in1, in2, in3, in4, in5, Wfc, bfc, bfv,
                                      mem2, counter);
    kB_spike_out<<<100, 512, 0, stream>>>(mem2, Wmlp, bmlp, spike, out, counter);
}

// Round 21
// 65.401 us; speedup vs baseline: 1.1858x; 1.1858x over previous
//
#include <hip/hip_runtime.h>

#define BB   8
#define NBL  2000
#define RR   10000
#define XDIM 2000

// ---------------- kernel A (split-K×4, champion): mem2[q][b][nb] = x·W_fc + biases
// 2000 blocks × 256 thr, 4 waves = column quarters. __launch_bounds__(256,4).
__global__ __launch_bounds__(256, 4) void kA_gemm(
    const float* __restrict__ in1, const float* __restrict__ in2,
    const float* __restrict__ in3, const float* __restrict__ in4,
    const float* __restrict__ in5,
    const float* __restrict__ Wfc, const float* __restrict__ bfc,
    const float* __restrict__ bfv, float* __restrict__ mem2,
    unsigned* __restrict__ counter)
{
    // re-arm the kernel-B barrier every call (stream order publishes it before kB)
    if (blockIdx.x == 0 && threadIdx.x == 0) *counter = 0u;

    const int tid  = threadIdx.x;
    const int wave = tid >> 6, lane = tid & 63;     // wave = column quarter 0..3
    const int nb    = blockIdx.x;                   // 0..1999
    const int rbase = nb * 5;

    float acc[5][BB];
    #pragma unroll
    for (int q = 0; q < 5; ++q)
        #pragma unroll
        for (int b = 0; b < BB; ++b) acc[q][b] = 0.f;

    #pragma unroll
    for (int i = 0; i < 2; ++i) {
        const int col = wave * 512 + i * 256 + (lane << 2);   // float4-aligned
        const bool valid = col < XDIM;              // tail: wave==3,i==1, lanes>=52
        const int wh  = col / 400;                  // concat segment (5 only if invalid)
        const int off = col - wh * 400;             // f4 never crosses a 400-boundary
        const float* xp = in1;
        xp = (wh == 1) ? in2 : xp;
        xp = (wh == 2) ? in3 : xp;
        xp = (wh == 3) ? in4 : xp;
        xp = (wh == 4) ? in5 : xp;

        float4 w[5];
        #pragma unroll
        for (int q = 0; q < 5; ++q)
            w[q] = valid ? *(const float4*)(Wfc + (size_t)(rbase + q) * XDIM + col)
                         : make_float4(0.f, 0.f, 0.f, 0.f);

        #pragma unroll
        for (int b = 0; b < BB; ++b) {
            float4 xv = valid ? *(const float4*)(xp + b * 400 + off)
                              : make_float4(0.f, 0.f, 0.f, 0.f);
            #pragma unroll
            for (int q = 0; q < 5; ++q)
                acc[q][b] += w[q].x * xv.x + w[q].y * xv.y + w[q].z * xv.z + w[q].w * xv.w;
        }
    }

    // intra-wave reduce -> LDS partials -> wave 0 finalizes
    __shared__ float part[4][5][BB];                // [wave][q][b], 640 B
    #pragma unroll
    for (int q = 0; q < 5; ++q) {
        #pragma unroll
        for (int b = 0; b < BB; ++b) {
            float v = acc[q][b];
            #pragma unroll
            for (int o = 32; o >= 1; o >>= 1) v += __shfl_xor(v, o, 64);
            if (lane == 0) part[wave][q][b] = v;
        }
    }
    __syncthreads();

    if (wave == 0 && lane < 40) {                   // 40 outputs: q = lane>>3, b = lane&7
        const int q = lane >> 3, b = lane & 7;
        const int r = rbase + q;
        const float v = part[0][q][b] + part[1][q][b] + part[2][q][b] + part[3][q][b];
        mem2[(q * BB + b) * NBL + nb] = v + bfc[r] + bfv[r] + 0.05f;
    }
}

// ---------------- kernel B (champion): select+spike -> barrier -> GEMV with W_mlp
// LDS-staged by non-select waves during the spin window.
__device__ __forceinline__ unsigned sortkey(float f) {
    unsigned u = __float_as_uint(f);
    return (u & 0x80000000u) ? ~u : (u | 0x80000000u);
}
__device__ __forceinline__ float unsortkey(unsigned u) {
    unsigned ub = (u & 0x80000000u) ? (u ^ 0x80000000u) : ~u;
    return __uint_as_float(ub);
}

__global__ __launch_bounds__(512) void kB_spike_out(
    const float* __restrict__ mem2, const float* __restrict__ Wmlp,
    const float* __restrict__ bmlp, float* __restrict__ spike_out,
    float* __restrict__ out, unsigned* __restrict__ counter)
{
    __shared__ float wlds[RR];                       // 40 KB: W_mlp row o
    const int tid = threadIdx.x;
    const int blk = blockIdx.x;                      // 100 blocks
    const bool is_sel = (blk < 40) && (tid < 64);    // select wave

    // ---- stage W_mlp[o] into LDS (all non-select threads; overlaps select below)
    if (!is_sel) {
        const int nstage = (blk < 40) ? 448 : 512;
        const int stid   = (blk < 40) ? (tid - 64) : tid;
        for (int j = stid; j < 2500; j += nstage) {
            const int col = j * 4;
            *(float4*)&wlds[col] = *(const float4*)(Wmlp + (size_t)blk * RR + col);
        }
    }

    // ---- phase A: blocks 0..39, wave 0 only — exact order stats + spike write
    if (is_sel) {
        const int b = blk / 5, k = blk - b * 5;
        const int lane = tid;
        const float* src = mem2 + (k * BB + b) * NBL;

        float    f[32];
        unsigned u[32];
        #pragma unroll
        for (int i = 0; i < 32; ++i) {
            int nb = i * 64 + lane;
            f[i] = (nb < NBL) ? src[nb] : 0.f;
            u[i] = (nb < NBL) ? sortkey(f[i]) : 0u;  // pad key = smallest
        }

        // rank-159 (160th largest): max X with count(u >= X) >= 160 (ballot+popc)
        unsigned X = 0;
        for (int bit = 31; bit >= 0; --bit) {
            unsigned cand = X | (1u << bit);
            int c = 0;
            #pragma unroll
            for (int i = 0; i < 32; ++i)
                c += (int)__popcll(__ballot(u[i] >= cand));
            if (c >= 160) X = cand;
        }
        const unsigned q2u = X;                      // mem_q2 (rank 159)

        int cge = 0;
        #pragma unroll
        for (int i = 0; i < 32; ++i)
            cge += (int)__popcll(__ballot(u[i] >= q2u));

        unsigned q1u;
        if (cge >= 161) {
            q1u = q2u;                               // ties reach rank 160
        } else {
            unsigned m = 0;
            #pragma unroll
            for (int i = 0; i < 32; ++i)
                if (u[i] < q2u && u[i] > m) m = u[i];
            #pragma unroll
            for (int o = 32; o >= 1; o >>= 1) {
                unsigned ot = __shfl_xor(m, o, 64);
                m = (ot > m) ? ot : m;
            }
            q1u = m;                                 // mem_q1 (rank 160)
        }

        const float q2 = unsortkey(q2u), q1 = unsortkey(q1u);
        const float nps = q1 + (q2 - q1) * 0.2f;

        #pragma unroll
        for (int i = 0; i < 32; ++i) {
            int nb = i * 64 + lane;
            if (nb < NBL)
                spike_out[b * RR + nb * 5 + k] = (f[i] - nps > 0.1f) ? 1.0f : 0.0f;
        }
        __threadfence();                             // release spike stores
        if (lane == 0) atomicAdd(counter, 1u);       // device-scope by default
    }

    // ---- barrier: all 100 blocks co-resident (<=256 CUs), spin on counter
    __syncthreads();                                 // also fences the LDS staging
    if (tid == 0) {
        while (__hip_atomic_load(counter, __ATOMIC_ACQUIRE, __HIP_MEMORY_SCOPE_AGENT) < 40u)
            __builtin_amdgcn_s_sleep(2);
        __threadfence();                             // belt-and-braces acquire
    }
    __syncthreads();

    // ---- phase B: block = output column o; out[b][o] = spike[b]·W_mlp[o] + b_mlp[o]
    const int o = blk;
    const int wave = tid >> 6, lane = tid & 63;

    float acc[BB];
    #pragma unroll
    for (int b = 0; b < BB; ++b) acc[b] = 0.f;

    #pragma unroll
    for (int i = 0; i < 5; ++i) {
        int col = i * 2048 + tid * 4;                // 512 thr × f4 = 2048 floats/iter
        if (col < RR) {                              // last valid f4 at 9996
            float4 w = *(const float4*)&wlds[col];
            #pragma unroll
            for (int b = 0; b < BB; ++b) {
                float4 s = *(const float4*)(spike_out + b * RR + col);
                acc[b] += w.x * s.x + w.y * s.y + w.z * s.z + w.w * s.w;
            }
        }
    }

    __shared__ float red[8][BB];
    #pragma unroll
    for (int b = 0; b < BB; ++b) {
        float v = acc[b];
        #pragma unroll
        for (int off = 32; off >= 1; off >>= 1) v += __shfl_xor(v, off, 64);
        if (lane == 0) red[wave][b] = v;
    }
    __syncthreads();
    if (tid < BB) {
        float v = 0.f;
        #pragma unroll
        for (int w = 0; w < 8; ++w) v += red[w][tid];
        out[tid * 100 + o] = v + bmlp[o];
    }
}

extern "C" void kernel_launch(void* const* d_in, const int* in_sizes, int n_in,
                              void* d_out, int out_size, void* d_ws, size_t ws_size,
                              hipStream_t stream) {
    const float* in1  = (const float*)d_in[0];
    const float* in2  = (const float*)d_in[1];
    const float* in3  = (const float*)d_in[2];
    const float* in4  = (const float*)d_in[3];
    const float* in5  = (const float*)d_in[4];
    const float* Wfc  = (const float*)d_in[5];
    const float* bfc  = (const float*)d_in[6];
    // d_in[7] = W_fv : multiplied by zero spikes — never read (saves 400 MB)
    const float* bfv  = (const float*)d_in[8];
    const float* Wmlp = (const float*)d_in[9];
    const float* bmlp = (const float*)d_in[10];

    float* out   = (float*)d_out;          // 8*100 = 800 floats
    float* spike = out + 800;              // 8*10000 floats (r_sumspike)

    float*    mem2    = (float*)d_ws;      // 80000 floats, layout [q][b][nb]
    unsigned* counter = (unsigned*)((char*)d_ws + 80000 * sizeof(float));

    kA_gemm<<<2000, 256, 0, stream>>>(in1, in2, in3, in4, in5, Wfc, bfc, bfv,
                                      mem2, counter);
    kB_spike_out<<<100, 512, 0, stream>>>(mem2, Wmlp, bmlp, spike, out, counter);
}

// Round 22
// 56.118 us; speedup vs baseline: 1.3819x; 1.1654x over previous
//
#include <hip/hip_runtime.h>

#define BB   8
#define NBL  2000
#define RR   10000
#define XDIM 2000

// v += dpp_permuted(v): single VALU op (v_add_f32 with DPP modifier), no DS pipe.
// CTRL must be compile-time. Butterfly-equivalent controls for a 16-lane SUM
// (verified lane-by-lane; NOT the shift controls of the R19 bug):
//   0xB1 = quad_perm[1,0,3,2]  (xor 1 within quad)
//   0x4E = quad_perm[2,3,0,1]  (xor 2 within quad)
//   0x141 = row_half_mirror    (i -> 7-i within 8: adds the other quad's sum)
//   0x140 = row_mirror         (i -> 15-i within 16: adds the other half-row's sum)
template <int CTRL>
__device__ __forceinline__ float dpp_add(float v) {
    int s = __builtin_amdgcn_update_dpp(0, __float_as_int(v), CTRL, 0xf, 0xf, true);
    return v + __int_as_float(s);
}

// ---------------- kernel A (split-K×4 champion; reduce diet): mem2[q][b][nb]
// 2000 blocks × 256 thr, 4 waves = column quarters. Reduce: 4 DPP adds (VALU,
// within-16 sum) + 2 shfl_xor (cross-row) — DS ops/wave 240 -> 80.
__global__ __launch_bounds__(256, 4) void kA_gemm(
    const float* __restrict__ in1, const float* __restrict__ in2,
    const float* __restrict__ in3, const float* __restrict__ in4,
    const float* __restrict__ in5,
    const float* __restrict__ Wfc, const float* __restrict__ bfc,
    const float* __restrict__ bfv, float* __restrict__ mem2,
    unsigned* __restrict__ counter)
{
    // re-arm the kernel-B barrier every call (stream order publishes it before kB)
    if (blockIdx.x == 0 && threadIdx.x == 0) *counter = 0u;

    const int tid  = threadIdx.x;
    const int wave = tid >> 6, lane = tid & 63;     // wave = column quarter 0..3
    const int nb    = blockIdx.x;                   // 0..1999
    const int rbase = nb * 5;

    float acc[5][BB];
    #pragma unroll
    for (int q = 0; q < 5; ++q)
        #pragma unroll
        for (int b = 0; b < BB; ++b) acc[q][b] = 0.f;

    #pragma unroll
    for (int i = 0; i < 2; ++i) {
        const int col = wave * 512 + i * 256 + (lane << 2);   // float4-aligned
        const bool valid = col < XDIM;              // tail: wave==3,i==1, lanes>=52
        const int wh  = col / 400;                  // concat segment (5 only if invalid)
        const int off = col - wh * 400;             // f4 never crosses a 400-boundary
        const float* xp = in1;
        xp = (wh == 1) ? in2 : xp;
        xp = (wh == 2) ? in3 : xp;
        xp = (wh == 3) ? in4 : xp;
        xp = (wh == 4) ? in5 : xp;

        float4 w[5];
        #pragma unroll
        for (int q = 0; q < 5; ++q)
            w[q] = valid ? *(const float4*)(Wfc + (size_t)(rbase + q) * XDIM + col)
                         : make_float4(0.f, 0.f, 0.f, 0.f);

        #pragma unroll
        for (int b = 0; b < BB; ++b) {
            float4 xv = valid ? *(const float4*)(xp + b * 400 + off)
                              : make_float4(0.f, 0.f, 0.f, 0.f);
            #pragma unroll
            for (int q = 0; q < 5; ++q)
                acc[q][b] += w[q].x * xv.x + w[q].y * xv.y + w[q].z * xv.z + w[q].w * xv.w;
        }
    }

    // intra-wave reduce: 4 DPP adds (within-16 sum, VALU pipe) + 2 cross-row shfl
    __shared__ float part[4][5][BB];                // [wave][q][b], 640 B
    #pragma unroll
    for (int q = 0; q < 5; ++q) {
        #pragma unroll
        for (int b = 0; b < BB; ++b) {
            float v = acc[q][b];
            v = dpp_add<0xB1>(v);                   // quad xor1
            v = dpp_add<0x4E>(v);                   // quad xor2
            v = dpp_add<0x141>(v);                  // row_half_mirror (other quad)
            v = dpp_add<0x140>(v);                  // row_mirror (other half-row)
            v += __shfl_xor(v, 16, 64);             // cross-row
            v += __shfl_xor(v, 32, 64);             // cross-half
            if (lane == 0) part[wave][q][b] = v;
        }
    }
    __syncthreads();

    if (wave == 0 && lane < 40) {                   // 40 outputs: q = lane>>3, b = lane&7
        const int q = lane >> 3, b = lane & 7;
        const int r = rbase + q;
        const float v = part[0][q][b] + part[1][q][b] + part[2][q][b] + part[3][q][b];
        mem2[(q * BB + b) * NBL + nb] = v + bfc[r] + bfv[r] + 0.05f;
    }
}

// ---------------- kernel B (champion, byte-identical): select+spike -> barrier ->
// GEMV with W_mlp LDS-staged by non-select waves during the spin window.
__device__ __forceinline__ unsigned sortkey(float f) {
    unsigned u = __float_as_uint(f);
    return (u & 0x80000000u) ? ~u : (u | 0x80000000u);
}
__device__ __forceinline__ float unsortkey(unsigned u) {
    unsigned ub = (u & 0x80000000u) ? (u ^ 0x80000000u) : ~u;
    return __uint_as_float(ub);
}

__global__ __launch_bounds__(512) void kB_spike_out(
    const float* __restrict__ mem2, const float* __restrict__ Wmlp,
    const float* __restrict__ bmlp, float* __restrict__ spike_out,
    float* __restrict__ out, unsigned* __restrict__ counter)
{
    __shared__ float wlds[RR];                       // 40 KB: W_mlp row o
    const int tid = threadIdx.x;
    const int blk = blockIdx.x;                      // 100 blocks
    const bool is_sel = (blk < 40) && (tid < 64);    // select wave

    // ---- stage W_mlp[o] into LDS (all non-select threads; overlaps select below)
    if (!is_sel) {
        const int nstage = (blk < 40) ? 448 : 512;
        const int stid   = (blk < 40) ? (tid - 64) : tid;
        for (int j = stid; j < 2500; j += nstage) {
            const int col = j * 4;
            *(float4*)&wlds[col] = *(const float4*)(Wmlp + (size_t)blk * RR + col);
        }
    }

    // ---- phase A: blocks 0..39, wave 0 only — exact order stats + spike write
    if (is_sel) {
        const int b = blk / 5, k = blk - b * 5;
        const int lane = tid;
        const float* src = mem2 + (k * BB + b) * NBL;

        float    f[32];
        unsigned u[32];
        #pragma unroll
        for (int i = 0; i < 32; ++i) {
            int nb = i * 64 + lane;
            f[i] = (nb < NBL) ? src[nb] : 0.f;
            u[i] = (nb < NBL) ? sortkey(f[i]) : 0u;  // pad key = smallest
        }

        // rank-159 (160th largest): max X with count(u >= X) >= 160 (ballot+popc)
        unsigned X = 0;
        for (int bit = 31; bit >= 0; --bit) {
            unsigned cand = X | (1u << bit);
            int c = 0;
            #pragma unroll
            for (int i = 0; i < 32; ++i)
                c += (int)__popcll(__ballot(u[i] >= cand));
            if (c >= 160) X = cand;
        }
        const unsigned q2u = X;                      // mem_q2 (rank 159)

        int cge = 0;
        #pragma unroll
        for (int i = 0; i < 32; ++i)
            cge += (int)__popcll(__ballot(u[i] >= q2u));

        unsigned q1u;
        if (cge >= 161) {
            q1u = q2u;                               // ties reach rank 160
        } else {
            unsigned m = 0;
            #pragma unroll
            for (int i = 0; i < 32; ++i)
                if (u[i] < q2u && u[i] > m) m = u[i];
            #pragma unroll
            for (int o = 32; o >= 1; o >>= 1) {
                unsigned ot = __shfl_xor(m, o, 64);
                m = (ot > m) ? ot : m;
            }
            q1u = m;                                 // mem_q1 (rank 160)
        }

        const float q2 = unsortkey(q2u), q1 = unsortkey(q1u);
        const float nps = q1 + (q2 - q1) * 0.2f;

        #pragma unroll
        for (int i = 0; i < 32; ++i) {
            int nb = i * 64 + lane;
            if (nb < NBL)
                spike_out[b * RR + nb * 5 + k] = (f[i] - nps > 0.1f) ? 1.0f : 0.0f;
        }
        __threadfence();                             // release spike stores
        if (lane == 0) atomicAdd(counter, 1u);       // device-scope by default
    }

    // ---- barrier: all 100 blocks co-resident (<=256 CUs), spin on counter
    __syncthreads();                                 // also fences the LDS staging
    if (tid == 0) {
        while (__hip_atomic_load(counter, __ATOMIC_ACQUIRE, __HIP_MEMORY_SCOPE_AGENT) < 40u)
            __builtin_amdgcn_s_sleep(2);
        __threadfence();                             // belt-and-braces acquire
    }
    __syncthreads();

    // ---- phase B: block = output column o; out[b][o] = spike[b]·W_mlp[o] + b_mlp[o]
    const int o = blk;
    const int wave = tid >> 6, lane = tid & 63;

    float acc[BB];
    #pragma unroll
    for (int b = 0; b < BB; ++b) acc[b] = 0.f;

    #pragma unroll
    for (int i = 0; i < 5; ++i) {
        int col = i * 2048 + tid * 4;                // 512 thr × f4 = 2048 floats/iter
        if (col < RR) {                              // last valid f4 at 9996
            float4 w = *(const float4*)&wlds[col];
            #pragma unroll
            for (int b = 0; b < BB; ++b) {
                float4 s = *(const float4*)(spike_out + b * RR + col);
                acc[b] += w.x * s.x + w.y * s.y + w.z * s.z + w.w * s.w;
            }
        }
    }

    __shared__ float red[8][BB];
    #pragma unroll
    for (int b = 0; b < BB; ++b) {
        float v = acc[b];
        #pragma unroll
        for (int off = 32; off >= 1; off >>= 1) v += __shfl_xor(v, off, 64);
        if (lane == 0) red[wave][b] = v;
    }
    __syncthreads();
    if (tid < BB) {
        float v = 0.f;
        #pragma unroll
        for (int w = 0; w < 8; ++w) v += red[w][tid];
        out[tid * 100 + o] = v + bmlp[o];
    }
}

extern "C" void kernel_launch(void* const* d_in, const int* in_sizes, int n_in,
                              void* d_out, int out_size, void* d_ws, size_t ws_size,
                              hipStream_t stream) {
    const float* in1  = (const float*)d_in[0];
    const float* in2  = (const float*)d_in[1];
    const float* in3  = (const float*)d_in[2];
    const float* in4  = (const float*)d_in[3];
    const float* in5  = (const float*)d_in[4];
    const float* Wfc  = (const float*)d_in[5];
    const float* bfc  = (const float*)d_in[6];
    // d_in[7] = W_fv : multiplied by zero spikes — never read (saves 400 MB)
    const float* bfv  = (const float*)d_in[8];
    const float* Wmlp = (const float*)d_in[9];
    const float* bmlp = (const float*)d_in[10];

    float* out   = (float*)d_out;          // 8*100 = 800 floats
    float* spike = out + 800;              // 8*10000 floats (r_sumspike)

    float*    mem2    = (float*)d_ws;      // 80000 floats, layout [q][b][nb]
    unsigned* counter = (unsigned*)((char*)d_ws + 80000 * sizeof(float));

    kA_gemm<<<2000, 256, 0, stream>>>(in1, in2, in3, in4, in5, Wfc, bfc, bfv,
                                      mem2, counter);
    kB_spike_out<<<100, 512, 0, stream>>>(mem2, Wmlp, bmlp, spike, out, counter);
}

// Round 23
// 50.909 us; speedup vs baseline: 1.5233x; 1.1023x over previous
//
#include <hip/hip_runtime.h>

#define BB   8
#define NBL  2000
#define RR   10000
#define XDIM 2000

// v += dpp_permuted(v): single VALU op (v_add_f32 with DPP modifier), no DS pipe.
// Full 64-lane sum sequence (standard GCN DPP reduction; result in lane 63):
//   0xB1  quad_perm[1,0,3,2]   xor1 within quad
//   0x4E  quad_perm[2,3,0,1]   xor2 within quad
//   0x141 row_half_mirror      adds other quad (within 8)
//   0x140 row_mirror           adds other half-row (within 16) -> lane holds row sum
//   0x142 row_bcast15          row1 += row0's sum; row3 += row2's sum
//   0x143 row_bcast31          rows2-3 += (row0+row1) -> lanes 48-63 hold TOTAL
template <int CTRL>
__device__ __forceinline__ float dpp_add(float v) {
    int s = __builtin_amdgcn_update_dpp(0, __float_as_int(v), CTRL, 0xf, 0xf, true);
    return v + __int_as_float(s);
}

// ---------------- kernel A (split-K×4 champion; zero-DS reduce): mem2[q][b][nb]
// 2000 blocks × 256 thr, 4 waves = column quarters. Reduce: 6 DPP adds, 0 DS ops
// (was 240 ds_swizzle pre-R22, 80 post-R22).
__global__ __launch_bounds__(256, 4) void kA_gemm(
    const float* __restrict__ in1, const float* __restrict__ in2,
    const float* __restrict__ in3, const float* __restrict__ in4,
    const float* __restrict__ in5,
    const float* __restrict__ Wfc, const float* __restrict__ bfc,
    const float* __restrict__ bfv, float* __restrict__ mem2,
    unsigned* __restrict__ counter)
{
    // re-arm the kernel-B barrier every call (stream order publishes it before kB)
    if (blockIdx.x == 0 && threadIdx.x == 0) *counter = 0u;

    const int tid  = threadIdx.x;
    const int wave = tid >> 6, lane = tid & 63;     // wave = column quarter 0..3
    const int nb    = blockIdx.x;                   // 0..1999
    const int rbase = nb * 5;

    float acc[5][BB];
    #pragma unroll
    for (int q = 0; q < 5; ++q)
        #pragma unroll
        for (int b = 0; b < BB; ++b) acc[q][b] = 0.f;

    #pragma unroll
    for (int i = 0; i < 2; ++i) {
        const int col = wave * 512 + i * 256 + (lane << 2);   // float4-aligned
        const bool valid = col < XDIM;              // tail: wave==3,i==1, lanes>=52
        const int wh  = col / 400;                  // concat segment (5 only if invalid)
        const int off = col - wh * 400;             // f4 never crosses a 400-boundary
        const float* xp = in1;
        xp = (wh == 1) ? in2 : xp;
        xp = (wh == 2) ? in3 : xp;
        xp = (wh == 3) ? in4 : xp;
        xp = (wh == 4) ? in5 : xp;

        float4 w[5];
        #pragma unroll
        for (int q = 0; q < 5; ++q)
            w[q] = valid ? *(const float4*)(Wfc + (size_t)(rbase + q) * XDIM + col)
                         : make_float4(0.f, 0.f, 0.f, 0.f);

        #pragma unroll
        for (int b = 0; b < BB; ++b) {
            float4 xv = valid ? *(const float4*)(xp + b * 400 + off)
                              : make_float4(0.f, 0.f, 0.f, 0.f);
            #pragma unroll
            for (int q = 0; q < 5; ++q)
                acc[q][b] += w[q].x * xv.x + w[q].y * xv.y + w[q].z * xv.z + w[q].w * xv.w;
        }
    }

    // intra-wave reduce: 6 DPP adds, all VALU pipe; total lands in lane 63
    __shared__ float part[4][5][BB];                // [wave][q][b], 640 B
    #pragma unroll
    for (int q = 0; q < 5; ++q) {
        #pragma unroll
        for (int b = 0; b < BB; ++b) {
            float v = acc[q][b];
            v = dpp_add<0xB1>(v);                   // quad xor1
            v = dpp_add<0x4E>(v);                   // quad xor2
            v = dpp_add<0x141>(v);                  // row_half_mirror
            v = dpp_add<0x140>(v);                  // row_mirror -> row sums
            v = dpp_add<0x142>(v);                  // row_bcast15
            v = dpp_add<0x143>(v);                  // row_bcast31 -> lane 63 total
            if (lane == 63) part[wave][q][b] = v;
        }
    }
    __syncthreads();

    if (wave == 0 && lane < 40) {                   // 40 outputs: q = lane>>3, b = lane&7
        const int q = lane >> 3, b = lane & 7;
        const int r = rbase + q;
        const float v = part[0][q][b] + part[1][q][b] + part[2][q][b] + part[3][q][b];
        mem2[(q * BB + b) * NBL + nb] = v + bfc[r] + bfv[r] + 0.05f;
    }
}

// ---------------- kernel B (champion, byte-identical): select+spike -> barrier ->
// GEMV with W_mlp LDS-staged by non-select waves during the spin window.
__device__ __forceinline__ unsigned sortkey(float f) {
    unsigned u = __float_as_uint(f);
    return (u & 0x80000000u) ? ~u : (u | 0x80000000u);
}
__device__ __forceinline__ float unsortkey(unsigned u) {
    unsigned ub = (u & 0x80000000u) ? (u ^ 0x80000000u) : ~u;
    return __uint_as_float(ub);
}

__global__ __launch_bounds__(512) void kB_spike_out(
    const float* __restrict__ mem2, const float* __restrict__ Wmlp,
    const float* __restrict__ bmlp, float* __restrict__ spike_out,
    float* __restrict__ out, unsigned* __restrict__ counter)
{
    __shared__ float wlds[RR];                       // 40 KB: W_mlp row o
    const int tid = threadIdx.x;
    const int blk = blockIdx.x;                      // 100 blocks
    const bool is_sel = (blk < 40) && (tid < 64);    // select wave

    // ---- stage W_mlp[o] into LDS (all non-select threads; overlaps select below)
    if (!is_sel) {
        const int nstage = (blk < 40) ? 448 : 512;
        const int stid   = (blk < 40) ? (tid - 64) : tid;
        for (int j = stid; j < 2500; j += nstage) {
            const int col = j * 4;
            *(float4*)&wlds[col] = *(const float4*)(Wmlp + (size_t)blk * RR + col);
        }
    }

    // ---- phase A: blocks 0..39, wave 0 only — exact order stats + spike write
    if (is_sel) {
        const int b = blk / 5, k = blk - b * 5;
        const int lane = tid;
        const float* src = mem2 + (k * BB + b) * NBL;

        float    f[32];
        unsigned u[32];
        #pragma unroll
        for (int i = 0; i < 32; ++i) {
            int nb = i * 64 + lane;
            f[i] = (nb < NBL) ? src[nb] : 0.f;
            u[i] = (nb < NBL) ? sortkey(f[i]) : 0u;  // pad key = smallest
        }

        // rank-159 (160th largest): max X with count(u >= X) >= 160 (ballot+popc)
        unsigned X = 0;
        for (int bit = 31; bit >= 0; --bit) {
            unsigned cand = X | (1u << bit);
            int c = 0;
            #pragma unroll
            for (int i = 0; i < 32; ++i)
                c += (int)__popcll(__ballot(u[i] >= cand));
            if (c >= 160) X = cand;
        }
        const unsigned q2u = X;                      // mem_q2 (rank 159)

        int cge = 0;
        #pragma unroll
        for (int i = 0; i < 32; ++i)
            cge += (int)__popcll(__ballot(u[i] >= q2u));

        unsigned q1u;
        if (cge >= 161) {
            q1u = q2u;                               // ties reach rank 160
        } else {
            unsigned m = 0;
            #pragma unroll
            for (int i = 0; i < 32; ++i)
                if (u[i] < q2u && u[i] > m) m = u[i];
            #pragma unroll
            for (int o = 32; o >= 1; o >>= 1) {
                unsigned ot = __shfl_xor(m, o, 64);
                m = (ot > m) ? ot : m;
            }
            q1u = m;                                 // mem_q1 (rank 160)
        }

        const float q2 = unsortkey(q2u), q1 = unsortkey(q1u);
        const float nps = q1 + (q2 - q1) * 0.2f;

        #pragma unroll
        for (int i = 0; i < 32; ++i) {
            int nb = i * 64 + lane;
            if (nb < NBL)
                spike_out[b * RR + nb * 5 + k] = (f[i] - nps > 0.1f) ? 1.0f : 0.0f;
        }
        __threadfence();                             // release spike stores
        if (lane == 0) atomicAdd(counter, 1u);       // device-scope by default
    }

    // ---- barrier: all 100 blocks co-resident (<=256 CUs), spin on counter
    __syncthreads();                                 // also fences the LDS staging
    if (tid == 0) {
        while (__hip_atomic_load(counter, __ATOMIC_ACQUIRE, __HIP_MEMORY_SCOPE_AGENT) < 40u)
            __builtin_amdgcn_s_sleep(2);
        __threadfence();                             // belt-and-braces acquire
    }
    __syncthreads();

    // ---- phase B: block = output column o; out[b][o] = spike[b]·W_mlp[o] + b_mlp[o]
    const int o = blk;
    const int wave = tid >> 6, lane = tid & 63;

    float acc[BB];
    #pragma unroll
    for (int b = 0; b < BB; ++b) acc[b] = 0.f;

    #pragma unroll
    for (int i = 0; i < 5; ++i) {
        int col = i * 2048 + tid * 4;                // 512 thr × f4 = 2048 floats/iter
        if (col < RR) {                              // last valid f4 at 9996
            float4 w = *(const float4*)&wlds[col];
            #pragma unroll
            for (int b = 0; b < BB; ++b) {
                float4 s = *(const float4*)(spike_out + b * RR + col);
                acc[b] += w.x * s.x + w.y * s.y + w.z * s.z + w.w * s.w;
            }
        }
    }

    __shared__ float red[8][BB];
    #pragma unroll
    for (int b = 0; b < BB; ++b) {
        float v = acc[b];
        #pragma unroll
        for (int off = 32; off >= 1; off >>= 1) v += __shfl_xor(v, off, 64);
        if (lane == 0) red[wave][b] = v;
    }
    __syncthreads();
    if (tid < BB) {
        float v = 0.f;
        #pragma unroll
        for (int w = 0; w < 8; ++w) v += red[w][tid];
        out[tid * 100 + o] = v + bmlp[o];
    }
}

extern "C" void kernel_launch(void* const* d_in, const int* in_sizes, int n_in,
                              void* d_out, int out_size, void* d_ws, size_t ws_size,
                              hipStream_t stream) {
    const float* in1  = (const float*)d_in[0];
    const float* in2  = (const float*)d_in[1];
    const float* in3  = (const float*)d_in[2];
    const float* in4  = (const float*)d_in[3];
    const float* in5  = (const float*)d_in[4];
    const float* Wfc  = (const float*)d_in[5];
    const float* bfc  = (const float*)d_in[6];
    // d_in[7] = W_fv : multiplied by zero spikes — never read (saves 400 MB)
    const float* bfv  = (const float*)d_in[8];
    const float* Wmlp = (const float*)d_in[9];
    const float* bmlp = (const float*)d_in[10];

    float* out   = (float*)d_out;          // 8*100 = 800 floats
    float* spike = out + 800;              // 8*10000 floats (r_sumspike)

    float*    mem2    = (float*)d_ws;      // 80000 floats, layout [q][b][nb]
    unsigned* counter = (unsigned*)((char*)d_ws + 80000 * sizeof(float));

    kA_gemm<<<2000, 256, 0, stream>>>(in1, in2, in3, in4, in5, Wfc, bfc, bfv,
                                      mem2, counter);
    kB_spike_out<<<100, 512, 0, stream>>>(mem2, Wmlp, bmlp, spike, out, counter);
}